// Round 13
// baseline (143.057 us; speedup 1.0000x reference)
//
#include <hip/hip_runtime.h>
#include <hip/hip_bf16.h>
#include <math.h>

typedef __attribute__((ext_vector_type(8))) short      bf16x8;
typedef __attribute__((ext_vector_type(8))) unsigned short u16x8;
typedef __attribute__((ext_vector_type(4))) unsigned short u16x4;
typedef __attribute__((ext_vector_type(4))) float       f32x4;

#define BB 8
#define CC 64
#define HH 128
#define WW 128
#define EE 16
#define DTXT 512
#define HWSZ 16384
#define WCHUNKS 4608      // per pair: 2half * 9k * 4slot * 64co 16B chunks
#define WHALF 2304        // one 32-ci half
#define HLO 18            // 16x16 tile + halo
#define HPX2 324
#define XCH (HPX2 * 8)    // 2592 16B chunks

static __device__ __forceinline__ unsigned short f2bf(float f) {
  unsigned u = __float_as_uint(f);
  unsigned r = (u + 0x7FFFu + ((u >> 16) & 1u)) >> 16;  // RNE
  return (unsigned short)r;
}
static __device__ __forceinline__ float bf2f(unsigned short s) {
  return __uint_as_float(((unsigned)s) << 16);
}

// exact-GELU via A&S 7.1.26 erf (|err| <= 1.5e-7, invisible at bf16)
static __device__ __forceinline__ float gelu_f(float x) {
  const float y = fabsf(x) * 0.70710678118654752f;
  const float t = __builtin_amdgcn_rcpf(1.f + 0.3275911f * y);
  float p = 1.061405429f;
  p = p * t - 1.453152027f;
  p = p * t + 1.421413741f;
  p = p * t - 0.284496736f;
  p = p * t + 0.254829592f;
  const float e = __expf(-y * y);
  const float erf_abs = 1.f - t * p * e;
  const float erf_s = copysignf(erf_abs, x);
  return 0.5f * x * (1.f + erf_s);
}

// ---------------------------------------------------------------- xtprep (+pool partials)
__global__ __launch_bounds__(256) void xtprep_kernel(const float* __restrict__ x,
                                                     unsigned short* __restrict__ xT,
                                                     float* __restrict__ pp) {
  __shared__ unsigned short lt[256 * 70];
  __shared__ float red[256];
  const int b = blockIdx.y, p0 = blockIdx.x * 256;
  const int t = threadIdx.x;
  const float* xb = x + (size_t)b * CC * HWSZ + p0;
#pragma unroll 8
  for (int ci = 0; ci < CC; ++ci)
    lt[t * 70 + ci] = f2bf(xb[(size_t)ci * HWSZ + t]);
  __syncthreads();
  unsigned short* dstb = xT + ((size_t)b * HWSZ + p0) * CC;
#pragma unroll
  for (int it = 0; it < 8; ++it) {
    const int j = it * 256 + t;
    const int px = j >> 3, s = j & 7;
    u16x8 v;
#pragma unroll
    for (int i = 0; i < 8; ++i) v[i] = lt[px * 70 + s * 8 + i];
    *(u16x8*)(dstb + (size_t)j * 8) = v;
  }
  const int ci = t & 63, q = t >> 6;
  float s = 0.f;
#pragma unroll 16
  for (int px = q * 64; px < q * 64 + 64; ++px) s += bf2f(lt[px * 70 + ci]);
  red[t] = s;
  __syncthreads();
  if (t < 64)
    pp[((size_t)b * 64 + blockIdx.x) * 64 + t] =
        red[t] + red[t + 64] + red[t + 128] + red[t + 192];
}

// ------------------------------------------------- conv core helpers
static __device__ __forceinline__ void stage_xt2(const u16x8* __restrict__ src,
                                                 u16x8* xt, int ty0, int tx0, int t) {
#pragma unroll
  for (int i = 0; i < 6; ++i) {
    const int idx = i * 512 + t;
    if (idx < XCH) {
      const int ph = idx >> 3, s = idx & 7;
      const int yy = ph / HLO, xx = ph - yy * HLO;
      const int gy = ty0 - 1 + yy, gx = tx0 - 1 + xx;
      u16x8 v = (u16x8){0, 0, 0, 0, 0, 0, 0, 0};
      if ((unsigned)gy < (unsigned)HH && (unsigned)gx < (unsigned)WW)
        v = src[(gy * WW + gx) * 8 + s];
      xt[ph * 8 + (s ^ (ph & 7))] = v;
    }
  }
}

static __device__ __forceinline__ void half_body2(const u16x8* xt, const u16x8* wt,
                                                  int half, int lane, int w,
                                                  f32x4 acc[2][4]) {
  const int ks = lane >> 4, ln = lane & 15;
#pragma unroll
  for (int kk = 0; kk < 9; ++kk) {
    const int dy = kk / 3, dx = kk % 3;
    bf16x8 a[4];
#pragma unroll
    for (int mf = 0; mf < 4; ++mf)
      a[mf] = __builtin_bit_cast(bf16x8, wt[(kk * 4 + ks) * 64 + mf * 16 + ln]);
#pragma unroll
    for (int nfr = 0; nfr < 2; ++nfr) {
      const int row = 2 * w + nfr + dy;
      const int col = ln + dx;
      const int ph = row * HLO + col;
      const bf16x8 bfr = __builtin_bit_cast(bf16x8,
                xt[ph * 8 + ((half * 4 + ks) ^ (ph & 7))]);
#pragma unroll
      for (int mf = 0; mf < 4; ++mf)
        acc[nfr][mf] = __builtin_amdgcn_mfma_f32_16x16x32_bf16(a[mf], bfr,
                                                               acc[nfr][mf], 0, 0, 0);
    }
  }
}

// repack one 32-ci half of w1[e] straight into LDS wt (fragment order).
// local = (k*4+s)*64+co; reads are L2-hot (w1[e] = 147 KB shared by 64 blocks).
static __device__ __forceinline__ void repack_wt(u16x8* wt, const float* __restrict__ w1e,
                                                 int half, int t) {
  const int ci_base = half * 32;
  for (int local = t; local < WHALF; local += 512) {
    const int co = local & 63;
    const int rest = local >> 6;   // 0..35
    const int s = rest & 3;
    const int k = rest >> 2;       // 0..8
    const int ci0 = ci_base + s * 8;
    u16x8 v;
#pragma unroll
    for (int i = 0; i < 8; ++i)
      v[i] = f2bf(w1e[((size_t)co * CC + ci0 + i) * 9 + k]);
    wt[local] = v;
  }
}

// ---------------------------------------------------------------- conv1 (fused gate+repack)
// grid (64 tiles 16x16, 8 b), 512 thr, 2 blocks/CU.
// Per block: redundant gate -> per-stage self-repack of w1 -> proven R9 MFMA
// pipeline + dual-scratch GELU epilogue. Also produces wp2/bg2p/aux for conv2.
// [Proven-don'ts: single-slot blocks (R11 -45%); dropping 8-chunk XOR swizzle
//  (R6 bank conflicts); cooperative mega-kernel (R10 launch failure).]
__global__ __launch_bounds__(512, 4) void conv1_kernel(
    const u16x8* __restrict__ xT,  const float* __restrict__ pp,
    const float* __restrict__ text, const float* __restrict__ Wx,
    const float* __restrict__ Wt,  const float* __restrict__ w1,
    const float* __restrict__ w2,  const float* __restrict__ b1,
    const float* __restrict__ b2,  unsigned short* __restrict__ wp2,
    float* __restrict__ bg2p,      float* __restrict__ aux_out,
    unsigned short* __restrict__ h) {
  __shared__ u16x8 xt[XCH];     // 41472 B
  __shared__ u16x8 wt[WHALF];   // 36864 B
  __shared__ float logits[BB][EE];
  __shared__ float gates[BB][EE];
  __shared__ int   s_eidx[16];
  __shared__ float s_gval[16];
  const int t = threadIdx.x, lane = t & 63, w = t >> 6;
  const int tile = blockIdx.x, b = blockIdx.y;
  const int id = b * 64 + tile;   // 0..511
  const int ty0 = (tile >> 3) * 16, tx0 = (tile & 7) * 16;

  // ---- gate phase (scratch aliased into xt/wt regions) ----
  {
    float* tx  = (float*)xt;                         // 16384 B
    float* pl  = (float*)(((char*)xt) + 16384);      // 2048 B  (<= 41472)
    float* wtl = (float*)wt;                         // 32768 B (<= 36864)
#pragma unroll
    for (int i = 0; i < 2; ++i)
      ((float4*)tx)[i * 512 + t] = ((const float4*)text)[i * 512 + t];
#pragma unroll
    for (int i = 0; i < 4; ++i)
      ((float4*)wtl)[i * 512 + t] = ((const float4*)Wt)[i * 512 + t];
    {
      const int bb = t >> 6, ci = t & 63;
      float s = 0.f;
#pragma unroll 8
      for (int blk = 0; blk < 64; ++blk) s += pp[((size_t)bb * 64 + blk) * 64 + ci];
      pl[bb * 64 + ci] = s * (1.f / (float)HWSZ);
    }
    __syncthreads();
    if (t < BB * EE) {
      const int bb = t >> 4, e = t & 15;
      float s = 0.f;
#pragma unroll 8
      for (int c = 0; c < CC; ++c) s += pl[bb * 64 + c] * Wx[c * EE + e];
#pragma unroll 8
      for (int d = 0; d < DTXT; ++d) s += tx[bb * DTXT + d] * wtl[d * EE + e];
      logits[bb][e] = s;
      gates[bb][e] = 0.f;
    }
    __syncthreads();
    if (t < BB) {
      const int bb = t;
      float v0 = -1e30f; int i0 = 0;
      for (int e = 0; e < EE; ++e) {
        float v = logits[bb][e];
        if (v > v0) { v0 = v; i0 = e; }
      }
      float v1 = -1e30f; int i1 = 0;
      for (int e = 0; e < EE; ++e) {
        if (e == i0) continue;
        float v = logits[bb][e];
        if (v > v1) { v1 = v; i1 = e; }
      }
      const float ex = expf(v1 - v0);
      const float g0 = 1.f / (1.f + ex);
      const float g1 = ex / (1.f + ex);
      gates[bb][i0] = g0;
      gates[bb][i1] = g1;
      s_eidx[2 * bb] = i0;      s_gval[2 * bb] = g0;
      s_eidx[2 * bb + 1] = i1;  s_gval[2 * bb + 1] = g1;
    }
    __syncthreads();
  }

  // ---- outputs for conv2: wp2 slice (144 chunks/block), bg2p, aux ----
  if (t < 144) {
    const int c16g = id * 144 + t;
    const int p = c16g / WCHUNKS;
    const int c16 = c16g - p * WCHUNKS;
    const int e = s_eidx[p];
    const float g = s_gval[p];
    const int co = c16 & 63;
    const int rest = c16 >> 6;
    const int s = rest & 3;
    const int ck = rest >> 2;
    const int k = ck % 9, half = ck / 9;
    const int ci0 = half * 32 + s * 8;
    const float* wsrc = w2 + (size_t)e * CC * CC * 9;
    u16x8 v;
#pragma unroll
    for (int i = 0; i < 8; ++i)
      v[i] = f2bf(g * wsrc[((size_t)co * CC + ci0 + i) * 9 + k]);
    *(u16x8*)(wp2 + (size_t)c16g * 8) = v;
  }
  if (tile == 0 && t < 128) {
    const int p = 2 * b + (t >> 6), co = t & 63;
    bg2p[p * CC + co] = s_gval[p] * b2[s_eidx[p] * CC + co];
  }
  if (id == 0 && t == 0) {
    float imp[EE];
    for (int e = 0; e < EE; ++e) {
      float s = 0.f;
      for (int bb = 0; bb < BB; ++bb) s += gates[bb][e];
      imp[e] = s;
    }
    float m = 0.f;
    for (int e = 0; e < EE; ++e) m += imp[e];
    m *= (1.f / EE);
    float v = 0.f;
    for (int e = 0; e < EE; ++e) { float d = imp[e] - m; v += d * d; }
    v *= (1.f / EE);
    aux_out[0] = v / (m * m + 1e-10f);
  }
  __syncthreads();   // gate scratch no longer needed; xt/wt free

  // ---- conv compute (R9-proven structure; wt self-repacked per stage) ----
  f32x4 acc[2][2][4];   // [slot][nfr][mf]
#pragma unroll
  for (int s = 0; s < 2; ++s)
#pragma unroll
    for (int i = 0; i < 2; ++i)
#pragma unroll
      for (int j = 0; j < 4; ++j) acc[s][i][j] = (f32x4){0.f, 0.f, 0.f, 0.f};

  stage_xt2(xT + (size_t)b * HWSZ * 8, xt, ty0, tx0, t);
  repack_wt(wt, w1 + (size_t)s_eidx[2 * b] * CC * CC * 9, 0, t);
  __syncthreads();

#pragma unroll
  for (int st = 0; st < 4; ++st) {
    const int slot = st >> 1, half = st & 1;
    __builtin_amdgcn_s_setprio(1);
    half_body2(xt, wt, half, lane, w, acc[slot]);
    __builtin_amdgcn_s_setprio(0);
    __syncthreads();
    if (st < 3) {
      const int nslot = (st + 1) >> 1, nhalf = (st + 1) & 1;
      repack_wt(wt, w1 + (size_t)s_eidx[2 * b + nslot] * CC * CC * 9, nhalf, t);
      __syncthreads();
    }
  }

  // epilogue: both slots in one pass; slot0 -> xt scratch, slot1 -> wt scratch
  unsigned short* lt0 = (unsigned short*)xt;
  unsigned short* lt1 = (unsigned short*)wt;
  const int ks = lane >> 4, ln = lane & 15;
  const int co_s = ks * 4;
  const int so = co_s >> 3, off = co_s & 7;
#pragma unroll
  for (int slot = 0; slot < 2; ++slot) {
    unsigned short* lt = slot ? lt1 : lt0;
    const int p = 2 * b + slot;
    const float* bsrc = b1 + s_eidx[p] * CC;
#pragma unroll
    for (int mf = 0; mf < 4; ++mf) {
      const float4 bv = *(const float4*)(bsrc + mf * 16 + co_s);
      const int s = mf * 2 + so;
#pragma unroll
      for (int nfr = 0; nfr < 2; ++nfr) {
        const int pxl = (2 * w + nfr) * 16 + ln;
        f32x4 v = acc[slot][nfr][mf];
        u16x4 pk = {f2bf(gelu_f(v.x + bv.x)), f2bf(gelu_f(v.y + bv.y)),
                    f2bf(gelu_f(v.z + bv.z)), f2bf(gelu_f(v.w + bv.w))};
        *(u16x4*)(lt + (pxl * 8 + (s ^ (pxl & 7))) * 8 + off) = pk;
      }
    }
  }
  __syncthreads();
  // coalesced copy-out: both slots, 4096 chunks
#pragma unroll
  for (int it = 0; it < 8; ++it) {
    const int j = it * 512 + t;
    const int slot = it >> 2;
    const int jj = j & 2047;
    const int px = jj >> 3, s = jj & 7;
    const u16x8 v = (slot ? (const u16x8*)wt : (const u16x8*)xt)[px * 8 + (s ^ (px & 7))];
    const int gpx = (ty0 + (px >> 4)) * WW + tx0 + (px & 15);
    *(u16x8*)(h + ((size_t)(2 * b + slot) * HWSZ + gpx) * CC + s * 8) = v;
  }
}

// ---------------------------------------------------------------- conv2
// grid (64 tiles 16x16, 8 b), 512 thr, 2 blocks/CU. R12 version unchanged.
__global__ __launch_bounds__(512, 4) void conv2_kernel(const u16x8* __restrict__ h,
                                                       const u16x8* __restrict__ wp2,
                                                       const float* __restrict__ bg2p,
                                                       float* __restrict__ out) {
  __shared__ u16x8 xt[XCH];
  __shared__ u16x8 wt[WHALF];
  const int t = threadIdx.x, lane = t & 63, w = t >> 6;
  const int tile = blockIdx.x, b = blockIdx.y;
  const int ty0 = (tile >> 3) * 16, tx0 = (tile & 7) * 16;

  f32x4 acc[2][4];
#pragma unroll
  for (int i = 0; i < 2; ++i)
#pragma unroll
    for (int j = 0; j < 4; ++j) acc[i][j] = (f32x4){0.f, 0.f, 0.f, 0.f};

  const u16x8* ws0 = wp2 + (size_t)(2 * b) * WCHUNKS;
  const u16x8* ws1 = wp2 + (size_t)(2 * b + 1) * WCHUNKS;
  const u16x8* src1 = h + (size_t)(2 * b + 1) * HWSZ * 8;
  u16x8 pw[5];

  stage_xt2(h + (size_t)(2 * b) * HWSZ * 8, xt, ty0, tx0, t);
#pragma unroll
  for (int i = 0; i < 5; ++i) {
    const int idx = i * 512 + t;
    if (idx < WHALF) wt[idx] = ws0[idx];
  }
  __syncthreads();

#pragma unroll
  for (int i = 0; i < 5; ++i) {
    const int idx = i * 512 + t;
    if (idx < WHALF) pw[i] = ws0[WHALF + idx];
  }
  u16x8 px[3];
#pragma unroll
  for (int i = 0; i < 3; ++i) {
    const int idx = i * 512 + t;
    const int ph = idx >> 3, s = idx & 7;
    const int yy = ph / HLO, xx = ph - yy * HLO;
    const int gy = ty0 - 1 + yy, gx = tx0 - 1 + xx;
    u16x8 v = (u16x8){0, 0, 0, 0, 0, 0, 0, 0};
    if ((unsigned)gy < (unsigned)HH && (unsigned)gx < (unsigned)WW)
      v = src1[(gy * WW + gx) * 8 + s];
    px[i] = v;
  }
  __builtin_amdgcn_s_setprio(1);
  half_body2(xt, wt, 0, lane, w, acc);
  __builtin_amdgcn_s_setprio(0);
  __syncthreads();
#pragma unroll
  for (int i = 0; i < 5; ++i) {
    const int idx = i * 512 + t;
    if (idx < WHALF) wt[idx] = pw[i];
  }
  __syncthreads();

#pragma unroll
  for (int i = 0; i < 5; ++i) {
    const int idx = i * 512 + t;
    if (idx < WHALF) pw[i] = ws1[idx];
  }
  __builtin_amdgcn_s_setprio(1);
  half_body2(xt, wt, 1, lane, w, acc);
  __builtin_amdgcn_s_setprio(0);
  __syncthreads();   // xt + wt readers done

#pragma unroll
  for (int i = 0; i < 3; ++i) {
    const int idx = i * 512 + t;
    const int ph = idx >> 3, s = idx & 7;
    xt[ph * 8 + (s ^ (ph & 7))] = px[i];
  }
#pragma unroll
  for (int i = 3; i < 6; ++i) {
    const int idx = i * 512 + t;
    if (idx < XCH) {
      const int ph = idx >> 3, s = idx & 7;
      const int yy = ph / HLO, xx = ph - yy * HLO;
      const int gy = ty0 - 1 + yy, gx = tx0 - 1 + xx;
      u16x8 v = (u16x8){0, 0, 0, 0, 0, 0, 0, 0};
      if ((unsigned)gy < (unsigned)HH && (unsigned)gx < (unsigned)WW)
        v = src1[(gy * WW + gx) * 8 + s];
      xt[ph * 8 + (s ^ (ph & 7))] = v;
    }
  }
#pragma unroll
  for (int i = 0; i < 5; ++i) {
    const int idx = i * 512 + t;
    if (idx < WHALF) wt[idx] = pw[i];
  }
  __syncthreads();

#pragma unroll
  for (int i = 0; i < 5; ++i) {
    const int idx = i * 512 + t;
    if (idx < WHALF) pw[i] = ws1[WHALF + idx];
  }
  __builtin_amdgcn_s_setprio(1);
  half_body2(xt, wt, 0, lane, w, acc);
  __builtin_amdgcn_s_setprio(0);
  __syncthreads();
#pragma unroll
  for (int i = 0; i < 5; ++i) {
    const int idx = i * 512 + t;
    if (idx < WHALF) wt[idx] = pw[i];
  }
  __syncthreads();

  __builtin_amdgcn_s_setprio(1);
  half_body2(xt, wt, 1, lane, w, acc);
  __builtin_amdgcn_s_setprio(0);

  const int co_s = (lane >> 4) * 4;
  const int ln = lane & 15;
#pragma unroll
  for (int mf = 0; mf < 4; ++mf) {
    const float4 ba = *(const float4*)(bg2p + (2 * b) * CC + mf * 16 + co_s);
    const float4 bb = *(const float4*)(bg2p + (2 * b + 1) * CC + mf * 16 + co_s);
    const float bx = ba.x + bb.x;
    const float by = ba.y + bb.y;
    const float bz = ba.z + bb.z;
    const float bw = ba.w + bb.w;
#pragma unroll
    for (int nfr = 0; nfr < 2; ++nfr) {
      const int row = 2 * w + nfr;
      const int gpx = (ty0 + row) * WW + tx0 + ln;
      f32x4 v = acc[nfr][mf];
      float* ob = out + (size_t)(b * CC + mf * 16 + co_s) * HWSZ + gpx;
      ob[0 * HWSZ] = v.x + bx;
      ob[1 * HWSZ] = v.y + by;
      ob[2 * HWSZ] = v.z + bz;
      ob[3 * HWSZ] = v.w + bw;
    }
  }
}

// ---------------------------------------------------------------- launch
extern "C" void kernel_launch(void* const* d_in, const int* in_sizes, int n_in,
                              void* d_out, int out_size, void* d_ws, size_t ws_size,
                              hipStream_t stream) {
  const float* x   = (const float*)d_in[0];
  const float* txt = (const float*)d_in[1];
  const float* Wx  = (const float*)d_in[2];
  const float* Wt  = (const float*)d_in[3];
  const float* w1  = (const float*)d_in[4];
  const float* b1  = (const float*)d_in[5];
  const float* w2  = (const float*)d_in[6];
  const float* b2  = (const float*)d_in[7];
  float* out = (float*)d_out;

  char* ws = (char*)d_ws;
  float* pp   = (float*)ws;                                  // 131,072 B
  float* bg2p = (float*)(ws + 131072);                       // 4,096 B
  unsigned short* wp2 = (unsigned short*)(ws + 135168);      // 1,179,648 B
  unsigned short* xT  = (unsigned short*)(ws + 1314816);     // 16,777,216 B
  unsigned short* h   = (unsigned short*)(ws + 18092032);    // 33,554,432 B

  xtprep_kernel<<<dim3(64, 8), 256, 0, stream>>>(x, xT, pp);
  conv1_kernel<<<dim3(64, 8), 512, 0, stream>>>((const u16x8*)xT, pp, txt, Wx, Wt,
                                                w1, w2, b1, b2, wp2, bg2p,
                                                out + (out_size - 1),
                                                (unsigned short*)h);
  conv2_kernel<<<dim3(64, 8), 512, 0, stream>>>((const u16x8*)h, (const u16x8*)wp2,
                                                bg2p, out);
}

// Round 14
// 95.435 us; speedup vs baseline: 1.4990x; 1.4990x over previous
//
#include <hip/hip_runtime.h>
#include <hip/hip_bf16.h>
#include <math.h>

typedef __attribute__((ext_vector_type(8))) short      bf16x8;
typedef __attribute__((ext_vector_type(8))) unsigned short u16x8;
typedef __attribute__((ext_vector_type(4))) unsigned short u16x4;
typedef __attribute__((ext_vector_type(4))) float       f32x4;

#define BB 8
#define CC 64
#define HH 128
#define WW 128
#define EE 16
#define DTXT 512
#define HWSZ 16384
#define WCHUNKS 4608      // per pair: 2half * 9k * 4slot * 64co 16B chunks
#define WHALF 2304        // one 32-ci half
#define HLO 18            // 16x16 tile + halo
#define HPX2 324
#define XCH (HPX2 * 8)    // 2592 16B chunks

// Proven-don'ts: single-slot conv blocks (R11 -45%); dropping the 8-chunk XOR
// swizzle (R6 bank conflicts); cooperative mega-kernel (R10 launch failure);
// inlining weight repack into conv1 (R13: 64x redundant gathers, conv1 2.4x).

static __device__ __forceinline__ unsigned short f2bf(float f) {
  unsigned u = __float_as_uint(f);
  unsigned r = (u + 0x7FFFu + ((u >> 16) & 1u)) >> 16;  // RNE
  return (unsigned short)r;
}
static __device__ __forceinline__ float bf2f(unsigned short s) {
  return __uint_as_float(((unsigned)s) << 16);
}

// exact-GELU via A&S 7.1.26 erf (|err| <= 1.5e-7, invisible at bf16)
static __device__ __forceinline__ float gelu_f(float x) {
  const float y = fabsf(x) * 0.70710678118654752f;
  const float t = __builtin_amdgcn_rcpf(1.f + 0.3275911f * y);
  float p = 1.061405429f;
  p = p * t - 1.453152027f;
  p = p * t + 1.421413741f;
  p = p * t - 0.284496736f;
  p = p * t + 0.254829592f;
  const float e = __expf(-y * y);
  const float erf_abs = 1.f - t * p * e;
  const float erf_s = copysignf(erf_abs, x);
  return 0.5f * x * (1.f + erf_s);
}

// ---------------------------------------------------------------- xtprep (+pool partials)
__global__ __launch_bounds__(256) void xtprep_kernel(const float* __restrict__ x,
                                                     unsigned short* __restrict__ xT,
                                                     float* __restrict__ pp) {
  __shared__ unsigned short lt[256 * 70];
  __shared__ float red[256];
  const int b = blockIdx.y, p0 = blockIdx.x * 256;
  const int t = threadIdx.x;
  const float* xb = x + (size_t)b * CC * HWSZ + p0;
#pragma unroll 8
  for (int ci = 0; ci < CC; ++ci)
    lt[t * 70 + ci] = f2bf(xb[(size_t)ci * HWSZ + t]);
  __syncthreads();
  unsigned short* dstb = xT + ((size_t)b * HWSZ + p0) * CC;
#pragma unroll
  for (int it = 0; it < 8; ++it) {
    const int j = it * 256 + t;
    const int px = j >> 3, s = j & 7;
    u16x8 v;
#pragma unroll
    for (int i = 0; i < 8; ++i) v[i] = lt[px * 70 + s * 8 + i];
    *(u16x8*)(dstb + (size_t)j * 8) = v;
  }
  const int ci = t & 63, q = t >> 6;
  float s = 0.f;
#pragma unroll 16
  for (int px = q * 64; px < q * 64 + 64; ++px) s += bf2f(lt[px * 70 + ci]);
  red[t] = s;
  __syncthreads();
  if (t < 64)
    pp[((size_t)b * 64 + blockIdx.x) * 64 + t] =
        red[t] + red[t + 64] + red[t + 128] + red[t + 192];
}

// ---------------------------------------------------------------- gwprep
// grid (16 pairs, 2 convs, 8 co-slices). Every block redundantly computes the
// gate (concurrent, no wall cost), stages its contiguous 18KB w-slice in LDS
// (coalesced), then repacks its 8-co slice of wp.
__global__ __launch_bounds__(256) void gwprep_kernel(const float* __restrict__ pp,
                                                     const float* __restrict__ text,
                                                     const float* __restrict__ Wx,
                                                     const float* __restrict__ Wt,
                                                     const float* __restrict__ w1,
                                                     const float* __restrict__ w2,
                                                     const float* __restrict__ b1,
                                                     const float* __restrict__ b2,
                                                     unsigned short* __restrict__ wp1,
                                                     unsigned short* __restrict__ wp2,
                                                     float* __restrict__ bg1,
                                                     float* __restrict__ bg2p,
                                                     float* __restrict__ aux_out) {
  __shared__ float pl[BB][CC];
  __shared__ float tx[BB * DTXT];
  __shared__ float wtl[DTXT * EE];
  __shared__ float lw[8 * 577];       // 8 co x 576, pad to 577 (conflict-free)
  __shared__ float logits[BB][EE];
  __shared__ float gates[BB][EE];
  __shared__ float imp[EE];
  __shared__ int   s_eidx[16];
  __shared__ float s_gval[16];
  const int t = threadIdx.x;

#pragma unroll
  for (int i = 0; i < BB * DTXT / 4 / 256; ++i)
    ((float4*)tx)[i * 256 + t] = ((const float4*)text)[i * 256 + t];
#pragma unroll
  for (int i = 0; i < DTXT * EE / 4 / 256; ++i)
    ((float4*)wtl)[i * 256 + t] = ((const float4*)Wt)[i * 256 + t];

#pragma unroll
  for (int jj = 0; jj < 2; ++jj) {
    const int j = jj * 256 + t;
    const int b = j >> 6, ci = j & 63;
    float s = 0.f;
#pragma unroll 8
    for (int blk = 0; blk < 64; ++blk) s += pp[((size_t)b * 64 + blk) * 64 + ci];
    pl[b][ci] = s * (1.f / (float)HWSZ);
  }
  __syncthreads();

  if (t < BB * EE) {
    const int b = t >> 4, e = t & 15;
    float s = 0.f;
#pragma unroll 8
    for (int c = 0; c < CC; ++c) s += pl[b][c] * Wx[c * EE + e];
#pragma unroll 8
    for (int d = 0; d < DTXT; ++d) s += tx[b * DTXT + d] * wtl[d * EE + e];
    logits[b][e] = s;
    gates[b][e] = 0.f;
  }
  __syncthreads();
  if (t < BB) {
    const int b = t;
    float v0 = -1e30f; int i0 = 0;
    for (int e = 0; e < EE; ++e) {
      float v = logits[b][e];
      if (v > v0) { v0 = v; i0 = e; }
    }
    float v1 = -1e30f; int i1 = 0;
    for (int e = 0; e < EE; ++e) {
      if (e == i0) continue;
      float v = logits[b][e];
      if (v > v1) { v1 = v; i1 = e; }
    }
    const float ex = expf(v1 - v0);
    const float g0 = 1.f / (1.f + ex);
    const float g1 = ex / (1.f + ex);
    gates[b][i0] = g0;
    gates[b][i1] = g1;
    s_eidx[2 * b] = i0;      s_gval[2 * b] = g0;
    s_eidx[2 * b + 1] = i1;  s_gval[2 * b + 1] = g1;
  }
  __syncthreads();

  const int p = blockIdx.x;
  const int conv = blockIdx.y;
  const int z = blockIdx.z;        // 0..7: 8-co slice
  const int e = s_eidx[p];
  const float g = conv ? s_gval[p] : 1.0f;

  if (z == 0 && t < CC) {
    if (conv == 0) bg1[p * CC + t] = b1[e * CC + t];
    else           bg2p[p * CC + t] = s_gval[p] * b2[e * CC + t];
  }
  if (p == 0 && conv == 0 && z == 0) {
    if (t < EE) {
      float s = 0.f;
      for (int b = 0; b < BB; ++b) s += gates[b][t];
      imp[t] = s;
    }
    __syncthreads();
    if (t == 0) {
      float m = 0.f;
      for (int ee = 0; ee < EE; ++ee) m += imp[ee];
      m *= (1.f / EE);
      float v = 0.f;
      for (int ee = 0; ee < EE; ++ee) { float d = imp[ee] - m; v += d * d; }
      v *= (1.f / EE);
      aux_out[0] = v / (m * m + 1e-10f);
    }
  }

  // stage this block's co-slice [z*8,(z+1)*8) of w[e]: 4608 floats, coalesced
  const float* wsl = (conv ? w2 : w1) + (size_t)e * CC * CC * 9 + (size_t)z * 8 * 576;
#pragma unroll
  for (int i = 0; i < 18; ++i) {
    const int f = i * 256 + t;          // f = co_l*576 + q
    const int co_l = f / 576, q = f - co_l * 576;
    lw[co_l * 577 + q] = wsl[f];
  }
  __syncthreads();

  // repack from LDS: 576 chunks; c16 = rest*64 + z*8 + co_l
  unsigned short* dst = (conv ? wp2 : wp1) + (size_t)p * WCHUNKS * 8;
  for (int j = t; j < 576; j += 256) {
    const int co_l = j & 7;
    const int rest = j >> 3;            // 0..71
    const int s = rest & 3;
    const int ck = rest >> 2;
    const int k = ck % 9, half = ck / 9;
    const int ci0 = half * 32 + s * 8;
    u16x8 v;
#pragma unroll
    for (int i = 0; i < 8; ++i)
      v[i] = f2bf(g * lw[co_l * 577 + (ci0 + i) * 9 + k]);
    const int c16 = rest * 64 + z * 8 + co_l;
    *(u16x8*)(dst + (size_t)c16 * 8) = v;
  }
}

// ------------------------------------------------- conv core helpers
static __device__ __forceinline__ void stage_xt2(const u16x8* __restrict__ src,
                                                 u16x8* xt, int ty0, int tx0, int t) {
#pragma unroll
  for (int i = 0; i < 6; ++i) {
    const int idx = i * 512 + t;
    if (idx < XCH) {
      const int ph = idx >> 3, s = idx & 7;
      const int yy = ph / HLO, xx = ph - yy * HLO;
      const int gy = ty0 - 1 + yy, gx = tx0 - 1 + xx;
      u16x8 v = (u16x8){0, 0, 0, 0, 0, 0, 0, 0};
      if ((unsigned)gy < (unsigned)HH && (unsigned)gx < (unsigned)WW)
        v = src[(gy * WW + gx) * 8 + s];
      xt[ph * 8 + (s ^ (ph & 7))] = v;
    }
  }
}

static __device__ __forceinline__ void half_body2(const u16x8* xt, const u16x8* wt,
                                                  int half, int lane, int w,
                                                  f32x4 acc[2][4]) {
  const int ks = lane >> 4, ln = lane & 15;
#pragma unroll
  for (int kk = 0; kk < 9; ++kk) {
    const int dy = kk / 3, dx = kk % 3;
    bf16x8 a[4];
#pragma unroll
    for (int mf = 0; mf < 4; ++mf)
      a[mf] = __builtin_bit_cast(bf16x8, wt[(kk * 4 + ks) * 64 + mf * 16 + ln]);
#pragma unroll
    for (int nfr = 0; nfr < 2; ++nfr) {
      const int row = 2 * w + nfr + dy;
      const int col = ln + dx;
      const int ph = row * HLO + col;
      const bf16x8 bfr = __builtin_bit_cast(bf16x8,
                xt[ph * 8 + ((half * 4 + ks) ^ (ph & 7))]);
#pragma unroll
      for (int mf = 0; mf < 4; ++mf)
        acc[nfr][mf] = __builtin_amdgcn_mfma_f32_16x16x32_bf16(a[mf], bfr,
                                                               acc[nfr][mf], 0, 0, 0);
    }
  }
}

// ---------------------------------------------------------------- conv1
// grid (64 tiles 16x16, 8 b), 512 thr, 2 blocks/CU. 4 wt stages pipelined
// (T14); setprio (T5); dual-scratch GELU epilogue (slot0->xt, slot1->wt).
__global__ __launch_bounds__(512, 4) void conv1_kernel(const u16x8* __restrict__ xT,
                                                       const u16x8* __restrict__ wp1,
                                                       const float* __restrict__ bg1,
                                                       unsigned short* __restrict__ h) {
  __shared__ u16x8 xt[XCH];     // 41472 B
  __shared__ u16x8 wt[WHALF];   // 36864 B -> 78336 B total
  const int t = threadIdx.x, lane = t & 63, w = t >> 6;
  const int tile = blockIdx.x, b = blockIdx.y;
  const int ty0 = (tile >> 3) * 16, tx0 = (tile & 7) * 16;

  f32x4 acc[2][2][4];   // [slot][nfr][mf]
#pragma unroll
  for (int s = 0; s < 2; ++s)
#pragma unroll
    for (int i = 0; i < 2; ++i)
#pragma unroll
      for (int j = 0; j < 4; ++j) acc[s][i][j] = (f32x4){0.f, 0.f, 0.f, 0.f};

  stage_xt2(xT + (size_t)b * HWSZ * 8, xt, ty0, tx0, t);
  {
    const u16x8* w0 = wp1 + (size_t)(2 * b) * WCHUNKS;
#pragma unroll
    for (int i = 0; i < 5; ++i) {
      const int idx = i * 512 + t;
      if (idx < WHALF) wt[idx] = w0[idx];
    }
  }
  __syncthreads();

  u16x8 pw[5];
#pragma unroll
  for (int st = 0; st < 4; ++st) {
    const int slot = st >> 1, half = st & 1;
    if (st < 3) {  // issue next stage's global loads before compute
      const u16x8* nw = wp1 + (size_t)(2 * b + ((st + 1) >> 1)) * WCHUNKS
                        + ((st + 1) & 1) * WHALF;
#pragma unroll
      for (int i = 0; i < 5; ++i) {
        const int idx = i * 512 + t;
        if (idx < WHALF) pw[i] = nw[idx];
      }
    }
    __builtin_amdgcn_s_setprio(1);
    half_body2(xt, wt, half, lane, w, acc[slot]);
    __builtin_amdgcn_s_setprio(0);
    __syncthreads();
    if (st < 3) {
#pragma unroll
      for (int i = 0; i < 5; ++i) {
        const int idx = i * 512 + t;
        if (idx < WHALF) wt[idx] = pw[i];
      }
      __syncthreads();
    }
  }

  // epilogue: both slots in one pass; slot0 -> xt scratch, slot1 -> wt scratch
  unsigned short* lt0 = (unsigned short*)xt;
  unsigned short* lt1 = (unsigned short*)wt;
  const int ks = lane >> 4, ln = lane & 15;
  const int co_s = ks * 4;
  const int so = co_s >> 3, off = co_s & 7;
#pragma unroll
  for (int slot = 0; slot < 2; ++slot) {
    unsigned short* lt = slot ? lt1 : lt0;
    const int p = 2 * b + slot;
#pragma unroll
    for (int mf = 0; mf < 4; ++mf) {
      const float4 bv = *(const float4*)(bg1 + p * CC + mf * 16 + co_s);
      const int s = mf * 2 + so;
#pragma unroll
      for (int nfr = 0; nfr < 2; ++nfr) {
        const int pxl = (2 * w + nfr) * 16 + ln;
        f32x4 v = acc[slot][nfr][mf];
        u16x4 pk = {f2bf(gelu_f(v.x + bv.x)), f2bf(gelu_f(v.y + bv.y)),
                    f2bf(gelu_f(v.z + bv.z)), f2bf(gelu_f(v.w + bv.w))};
        *(u16x4*)(lt + (pxl * 8 + (s ^ (pxl & 7))) * 8 + off) = pk;
      }
    }
  }
  __syncthreads();
  // coalesced copy-out: both slots, 4096 chunks
#pragma unroll
  for (int it = 0; it < 8; ++it) {
    const int j = it * 512 + t;
    const int slot = it >> 2;
    const int jj = j & 2047;
    const int px = jj >> 3, s = jj & 7;
    const u16x8 v = (slot ? (const u16x8*)wt : xt)[px * 8 + (s ^ (px & 7))];
    const int gpx = (ty0 + (px >> 4)) * WW + tx0 + (px & 15);
    *(u16x8*)(h + ((size_t)(2 * b + slot) * HWSZ + gpx) * CC + s * 8) = v;
  }
}

// ---------------------------------------------------------------- conv2
// grid (64 tiles 16x16, 8 b), 512 thr, 2 blocks/CU. Full wt prefetch pipeline
// + slot-1 xt partial register prefetch (first 1536 chunks, T14).
__global__ __launch_bounds__(512, 4) void conv2_kernel(const u16x8* __restrict__ h,
                                                       const u16x8* __restrict__ wp2,
                                                       const float* __restrict__ bg2p,
                                                       float* __restrict__ out) {
  __shared__ u16x8 xt[XCH];
  __shared__ u16x8 wt[WHALF];
  const int t = threadIdx.x, lane = t & 63, w = t >> 6;
  const int tile = blockIdx.x, b = blockIdx.y;
  const int ty0 = (tile >> 3) * 16, tx0 = (tile & 7) * 16;

  f32x4 acc[2][4];
#pragma unroll
  for (int i = 0; i < 2; ++i)
#pragma unroll
    for (int j = 0; j < 4; ++j) acc[i][j] = (f32x4){0.f, 0.f, 0.f, 0.f};

  const u16x8* ws0 = wp2 + (size_t)(2 * b) * WCHUNKS;
  const u16x8* ws1 = wp2 + (size_t)(2 * b + 1) * WCHUNKS;
  const u16x8* src1 = h + (size_t)(2 * b + 1) * HWSZ * 8;
  u16x8 pw[5];

  stage_xt2(h + (size_t)(2 * b) * HWSZ * 8, xt, ty0, tx0, t);
#pragma unroll
  for (int i = 0; i < 5; ++i) {
    const int idx = i * 512 + t;
    if (idx < WHALF) wt[idx] = ws0[idx];
  }
  __syncthreads();

  // prefetch wt s0h1 + first 1536 chunks of slot-1 xt (T14)
#pragma unroll
  for (int i = 0; i < 5; ++i) {
    const int idx = i * 512 + t;
    if (idx < WHALF) pw[i] = ws0[WHALF + idx];
  }
  u16x8 px[3];
#pragma unroll
  for (int i = 0; i < 3; ++i) {
    const int idx = i * 512 + t;
    const int ph = idx >> 3, s = idx & 7;
    const int yy = ph / HLO, xx = ph - yy * HLO;
    const int gy = ty0 - 1 + yy, gx = tx0 - 1 + xx;
    u16x8 v = (u16x8){0, 0, 0, 0, 0, 0, 0, 0};
    if ((unsigned)gy < (unsigned)HH && (unsigned)gx < (unsigned)WW)
      v = src1[(gy * WW + gx) * 8 + s];
    px[i] = v;
  }
  __builtin_amdgcn_s_setprio(1);
  half_body2(xt, wt, 0, lane, w, acc);
  __builtin_amdgcn_s_setprio(0);
  __syncthreads();
#pragma unroll
  for (int i = 0; i < 5; ++i) {
    const int idx = i * 512 + t;
    if (idx < WHALF) wt[idx] = pw[i];
  }
  __syncthreads();

#pragma unroll
  for (int i = 0; i < 5; ++i) {
    const int idx = i * 512 + t;
    if (idx < WHALF) pw[i] = ws1[idx];
  }
  __builtin_amdgcn_s_setprio(1);
  half_body2(xt, wt, 1, lane, w, acc);
  __builtin_amdgcn_s_setprio(0);
  __syncthreads();   // xt + wt readers done

  // restage xt for slot1: prefetched head + staged tail; wt <- prefetched s1h0
#pragma unroll
  for (int i = 0; i < 3; ++i) {
    const int idx = i * 512 + t;
    const int ph = idx >> 3, s = idx & 7;
    xt[ph * 8 + (s ^ (ph & 7))] = px[i];
  }
#pragma unroll
  for (int i = 3; i < 6; ++i) {
    const int idx = i * 512 + t;
    if (idx < XCH) {
      const int ph = idx >> 3, s = idx & 7;
      const int yy = ph / HLO, xx = ph - yy * HLO;
      const int gy = ty0 - 1 + yy, gx = tx0 - 1 + xx;
      u16x8 v = (u16x8){0, 0, 0, 0, 0, 0, 0, 0};
      if ((unsigned)gy < (unsigned)HH && (unsigned)gx < (unsigned)WW)
        v = src1[(gy * WW + gx) * 8 + s];
      xt[ph * 8 + (s ^ (ph & 7))] = v;
    }
  }
#pragma unroll
  for (int i = 0; i < 5; ++i) {
    const int idx = i * 512 + t;
    if (idx < WHALF) wt[idx] = pw[i];
  }
  __syncthreads();

  // slot1 half0 (prefetch s1h1)
#pragma unroll
  for (int i = 0; i < 5; ++i) {
    const int idx = i * 512 + t;
    if (idx < WHALF) pw[i] = ws1[WHALF + idx];
  }
  __builtin_amdgcn_s_setprio(1);
  half_body2(xt, wt, 0, lane, w, acc);
  __builtin_amdgcn_s_setprio(0);
  __syncthreads();
#pragma unroll
  for (int i = 0; i < 5; ++i) {
    const int idx = i * 512 + t;
    if (idx < WHALF) wt[idx] = pw[i];
  }
  __syncthreads();

  __builtin_amdgcn_s_setprio(1);
  half_body2(xt, wt, 1, lane, w, acc);
  __builtin_amdgcn_s_setprio(0);

  const int co_s = (lane >> 4) * 4;
  const int ln = lane & 15;
#pragma unroll
  for (int mf = 0; mf < 4; ++mf) {
    const float4 ba = *(const float4*)(bg2p + (2 * b) * CC + mf * 16 + co_s);
    const float4 bb = *(const float4*)(bg2p + (2 * b + 1) * CC + mf * 16 + co_s);
    const float bx = ba.x + bb.x;
    const float by = ba.y + bb.y;
    const float bz = ba.z + bb.z;
    const float bw = ba.w + bb.w;
#pragma unroll
    for (int nfr = 0; nfr < 2; ++nfr) {
      const int row = 2 * w + nfr;
      const int gpx = (ty0 + row) * WW + tx0 + ln;
      f32x4 v = acc[nfr][mf];
      float* ob = out + (size_t)(b * CC + mf * 16 + co_s) * HWSZ + gpx;
      ob[0 * HWSZ] = v.x + bx;
      ob[1 * HWSZ] = v.y + by;
      ob[2 * HWSZ] = v.z + bz;
      ob[3 * HWSZ] = v.w + bw;
    }
  }
}

// ---------------------------------------------------------------- launch
extern "C" void kernel_launch(void* const* d_in, const int* in_sizes, int n_in,
                              void* d_out, int out_size, void* d_ws, size_t ws_size,
                              hipStream_t stream) {
  const float* x   = (const float*)d_in[0];
  const float* txt = (const float*)d_in[1];
  const float* Wx  = (const float*)d_in[2];
  const float* Wt  = (const float*)d_in[3];
  const float* w1  = (const float*)d_in[4];
  const float* b1  = (const float*)d_in[5];
  const float* w2  = (const float*)d_in[6];
  const float* b2  = (const float*)d_in[7];
  float* out = (float*)d_out;

  char* ws = (char*)d_ws;
  float* pp   = (float*)ws;                                  // 131,072 B
  float* bg1  = (float*)(ws + 131072);                       // 4,096 B
  float* bg2p = (float*)(ws + 135168);                       // 4,096 B
  unsigned short* wp1 = (unsigned short*)(ws + 139264);      // 1,179,648 B
  unsigned short* wp2 = (unsigned short*)(ws + 1318912);     // 1,179,648 B
  unsigned short* xT  = (unsigned short*)(ws + 2498560);     // 16,777,216 B
  unsigned short* h   = (unsigned short*)(ws + 19275776);    // 33,554,432 B

  xtprep_kernel<<<dim3(64, 8), 256, 0, stream>>>(x, xT, pp);
  gwprep_kernel<<<dim3(16, 2, 8), 256, 0, stream>>>(pp, txt, Wx, Wt, w1, w2, b1, b2,
                                                    wp1, wp2, bg1, bg2p,
                                                    out + (out_size - 1));
  conv1_kernel<<<dim3(64, 8), 512, 0, stream>>>((const u16x8*)xT, (const u16x8*)wp1,
                                                bg1, (unsigned short*)h);
  conv2_kernel<<<dim3(64, 8), 512, 0, stream>>>((const u16x8*)h, (const u16x8*)wp2,
                                                bg2p, out);
}